// Round 12
// baseline (2333.578 us; speedup 1.0000x reference)
//
#include <hip/hip_runtime.h>
#include <hip/hip_bf16.h>
#include <stdint.h>

#define D_MODEL 1024
#define D_FF    4096
#define N_ZONES 8
#define TOPK    3
#define RH      256
#define BATCH   16
#define SEQ     2048
#define NPAIR   (BATCH * TOPK)

typedef __bf16 bf16;
typedef __bf16 bf16x8 __attribute__((ext_vector_type(8)));
typedef __bf16 bf16x4 __attribute__((ext_vector_type(4)));
typedef float  f32x4  __attribute__((ext_vector_type(4)));

// ---------------- helpers ----------------

__device__ __forceinline__ void gload16(const void* g, void* l) {
  __builtin_amdgcn_global_load_lds((const __attribute__((address_space(1))) void*)g,
                                   (__attribute__((address_space(3))) void*)l,
                                   16, 0, 0);
}

__device__ __forceinline__ float gelu_tanh(float x) {
  float inner = 0.7978845608028654f * (x + 0.044715f * x * x * x);
  float t = __expf(2.0f * inner);
  float th = 1.0f - 2.0f / (t + 1.0f);
  return 0.5f * x * (1.0f + th);
}

__device__ __forceinline__ void xcd_remap(int& bx, int& by, int& bz) {
  int lin = blockIdx.x + gridDim.x * (blockIdx.y + gridDim.y * blockIdx.z);
  int nwg = gridDim.x * gridDim.y * gridDim.z;
  int ns  = (lin & 7) * (nwg >> 3) + (lin >> 3);
  bx = ns % gridDim.x; int rest = ns / gridDim.x;
  by = rest % gridDim.y; bz = rest / gridDim.y;
}

// ---------------- pooling ----------------

__global__ void pool_partial_kernel(const float* __restrict__ x, float* __restrict__ partial) {
  int sc = blockIdx.x;
  int b  = blockIdx.y;
  int tid = threadIdx.x;
  const float* xp = x + ((size_t)b * SEQ + (size_t)sc * 256) * D_MODEL;
  for (int i = 0; i < D_MODEL / 256; ++i) {
    int d = tid + i * 256;
    float s = 0.f;
    for (int ss = 0; ss < 256; ++ss) s += xp[(size_t)ss * D_MODEL + d];
    partial[((size_t)sc * BATCH + b) * D_MODEL + d] = s;
  }
}

__global__ void pool_final_kernel(const float* __restrict__ partial, float* __restrict__ pooled) {
  int b = blockIdx.x;
  int tid = threadIdx.x;
  for (int i = 0; i < D_MODEL / 256; ++i) {
    int d = tid + i * 256;
    float s = 0.f;
    for (int sc = 0; sc < 8; ++sc) s += partial[((size_t)sc * BATCH + b) * D_MODEL + d];
    pooled[b * D_MODEL + d] = s * (1.0f / SEQ);
  }
}

// ---------------- router ----------------

__global__ void router_kernel(const float* __restrict__ pooled,
                              const float* __restrict__ W1, const float* __restrict__ b1,
                              const float* __restrict__ W2, const float* __restrict__ b2,
                              int* __restrict__ route_e, float* __restrict__ route_w) {
  __shared__ float pld[D_MODEL];
  __shared__ float hls[RH];
  __shared__ float lg[N_ZONES];
  const int b = blockIdx.x;
  const int j = threadIdx.x;

  for (int i = 0; i < D_MODEL / RH; ++i) pld[j + i * RH] = pooled[b * D_MODEL + j + i * RH];
  __syncthreads();

  float acc = b1[j];
#pragma unroll 8
  for (int k = 0; k < D_MODEL; ++k) acc += pld[k] * W1[k * RH + j];
  hls[j] = tanhf(acc);
  __syncthreads();

  if (j < N_ZONES) {
    float s = b2[j];
    for (int t = 0; t < RH; ++t) s += hls[t] * W2[t * N_ZONES + j];
    lg[j] = s;
  }
  __syncthreads();

  if (j == 0) {
    float m = lg[0];
    for (int e = 1; e < N_ZONES; ++e) m = fmaxf(m, lg[e]);
    float p[N_ZONES]; float sum = 0.f;
    for (int e = 0; e < N_ZONES; ++e) { p[e] = expf(lg[e] - m); sum += p[e]; }
    int used[N_ZONES] = {0};
    int idx[TOPK]; float tv[TOPK]; float tsum = 0.f;
    for (int r = 0; r < TOPK; ++r) {
      int best = 0; float bv = -1.f;
      for (int e = 0; e < N_ZONES; ++e)
        if (!used[e] && p[e] > bv) { bv = p[e]; best = e; }
      used[best] = 1; idx[r] = best; tv[r] = bv / sum; tsum += bv / sum;
    }
    for (int r = 0; r < TOPK; ++r) {
      route_e[b * TOPK + r] = idx[r];
      route_w[b * TOPK + r] = tv[r] / tsum;
    }
  }
}

__global__ void sort_pairs_kernel(const int* __restrict__ route_e, int* __restrict__ perm) {
  if (threadIdx.x == 0 && blockIdx.x == 0) {
    int p = 0;
    for (int e = 0; e < N_ZONES; ++e)
      for (int i = 0; i < NPAIR; ++i)
        if (route_e[i] == e) perm[p++] = i;
  }
}

// ---------------- conversions (convert + out-init fused) ----------------

__global__ void convert_x_kernel(const float* __restrict__ x, bf16* __restrict__ xb,
                                 float* __restrict__ out) {
  size_t i = ((size_t)blockIdx.x * blockDim.x + threadIdx.x) * 8;
  const float4* p = (const float4*)(x + i);
  float4 v0 = p[0], v1 = p[1];
  bf16x8 o;
  o[0] = (bf16)v0.x; o[1] = (bf16)v0.y; o[2] = (bf16)v0.z; o[3] = (bf16)v0.w;
  o[4] = (bf16)v1.x; o[5] = (bf16)v1.y; o[6] = (bf16)v1.z; o[7] = (bf16)v1.w;
  *(bf16x8*)(xb + i) = o;
  float4* q = (float4*)(out + i);
  q[0] = v0; q[1] = v1;                 // out pre-init to x (gemm2 atomic-adds on top)
}

__global__ void transpose_kernel(const float* __restrict__ src, bf16* __restrict__ dst, int R, int C) {
  __shared__ float tile[64][65];
  int e = blockIdx.z;
  const float* s = src + (size_t)e * R * C;
  bf16* d = dst + (size_t)e * R * C;
  int r0 = blockIdx.y * 64, c0 = blockIdx.x * 64;
  int tc = threadIdx.x & 63, tr4 = threadIdx.x >> 6;
  for (int i = 0; i < 16; ++i) {
    int r = i * 4 + tr4;
    tile[r][tc] = s[(size_t)(r0 + r) * C + (c0 + tc)];
  }
  __syncthreads();
  for (int i = 0; i < 16; ++i) {
    int cc = i * 4 + tr4;
    d[(size_t)(c0 + cc) * R + (r0 + tc)] = (bf16)tile[tc][cc];
  }
}

// ---------------- shared per-kernel decls ----------------

#define GEMM_DECLS                                                             \
  const int tid = threadIdx.x;                                                 \
  const int lane = tid & 63;                                                   \
  const int w = tid >> 6;                                                      \
  const int wm = w >> 2, wn = w & 3;                                           \
  const int fr = lane & 15, fq = lane >> 4;                                    \
  const int swz = (((lane & 3) ^ ((lane >> 3) & 3)) * 8);                      \
  const int swr = ((fq ^ ((fr >> 1) & 3)) * 8);                                \
  const int srow = lane >> 2;

// =====================================================================
// Fat-phase ring-2 core (r9/r10-proven): 256x256, BK=64 (2 ksteps of 32).
// LDS As/Bs = [2 buf][2 ks][256x32] bf16 = 64KB each -> 128KB, 1 block/CU.
// Phase (t,ks): vmcnt(4); barrier; free zone {12 ds_read (B first), stage 4
// gloads, 32 MFMA}; trailing sched_barrier(0).
// SR=256 (r11): per-slice L3 working set = hbuf 96MB + WaT 64 + WbT 64 = 224MB
// < 256MB Infinity Cache -> hbuf stays L3-resident between gemm1 and gemm2
// (at SR=512 it was 320MB -> thrash; gemm2 FETCH 291MB/slice proved re-fetch).
// =====================================================================

#define FP_STAGE4(buf_, ks_, SA_, SB_, ld_, kcb_)                              \
  { const bf16* _sa = (SA_) + (size_t)(w * 16 + srow) * (ld_) + (kcb_) + swz;  \
    bf16* _la = &As[((buf_) * 2 + (ks_)) * 8192] + w * 512;                    \
    gload16(_sa, _la);                                                         \
    gload16(_sa + (size_t)128 * (ld_), _la + 4096);                            \
    const bf16* _sb = (SB_) + (size_t)(w * 16 + srow) * (ld_) + (kcb_) + swz;  \
    bf16* _lb = &Bs[((buf_) * 2 + (ks_)) * 8192] + w * 512;                    \
    gload16(_sb, _lb);                                                         \
    gload16(_sb + (size_t)128 * (ld_), _lb + 4096); }

#define FP_DSRD12(buf_, ks_)                                                   \
  { const bf16* Bh = &Bs[((buf_) * 2 + (ks_)) * 8192] + (size_t)(wn * 64 + fr) * 32 + swr; \
    _Pragma("unroll")                                                          \
    for (int i = 0; i < 4; ++i) fB[i] = *(const bf16x8*)(Bh + i * 512);        \
    const bf16* Ah = &As[((buf_) * 2 + (ks_)) * 8192] + (size_t)(wm * 128 + fr) * 32 + swr; \
    _Pragma("unroll")                                                          \
    for (int i = 0; i < 8; ++i) fA[i] = *(const bf16x8*)(Ah + i * 512); }

// SWAP_: 1 = mfma(fB,fA) (cols packed by fq -> dense 8B stores), 0 = mfma(fA,fB)
// (rows by fq*4+j, cols by fr -> line-covering atomic layout).
#define FP_PHASE(rbuf_, rks_, sbuf_, sks_, SA_, SB_, ld_, kcb_, SWAP_)         \
  { asm volatile("s_waitcnt vmcnt(4)" ::: "memory");                           \
    __builtin_amdgcn_s_barrier();                                              \
    __builtin_amdgcn_sched_barrier(0);                                         \
    FP_DSRD12(rbuf_, rks_);                                                    \
    FP_STAGE4(sbuf_, sks_, SA_, SB_, ld_, kcb_);                               \
    __builtin_amdgcn_s_setprio(1);                                             \
    _Pragma("unroll")                                                          \
    for (int mi = 0; mi < 8; ++mi)                                             \
      _Pragma("unroll")                                                        \
      for (int ni = 0; ni < 4; ++ni)                                           \
        acc[mi][ni] = (SWAP_)                                                  \
          ? __builtin_amdgcn_mfma_f32_16x16x32_bf16(fB[ni], fA[mi], acc[mi][ni], 0, 0, 0) \
          : __builtin_amdgcn_mfma_f32_16x16x32_bf16(fA[mi], fB[ni], acc[mi][ni], 0, 0, 0); \
    __builtin_amdgcn_s_setprio(0);                                             \
    __builtin_amdgcn_sched_barrier(0); }

// GEMM1: h = gelu(xb @ Wa[e]) * w_r  (swapped operands -> dense packed epilogue)
__launch_bounds__(512, 2)
__global__ void gemm1_kernel(const bf16* __restrict__ xb, const bf16* __restrict__ WaT,
                             const int* __restrict__ route_e, const float* __restrict__ route_w,
                             const int* __restrict__ perm,
                             bf16* __restrict__ hbuf, int s_base, int SR) {
  __shared__ bf16 As[2 * 2 * 8192];
  __shared__ bf16 Bs[2 * 2 * 8192];
  int bx, by, bz;
  xcd_remap(bx, by, bz);
  const int pair = perm[bz];          // expert-sorted: XCD chunk shares WaT panels
  const int b = pair / TOPK;
  const int e = route_e[pair];
  const float wr = route_w[pair];
  const int m0 = by * 256;
  const int n0 = bx * 256;
  GEMM_DECLS
  f32x4 acc[8][4] = {};
  bf16x8 fA[8], fB[4];

  const bf16* Ag = xb  + ((size_t)b * SEQ + (size_t)(s_base + m0)) * D_MODEL;
  const bf16* Bg = WaT + ((size_t)e * D_FF + n0) * D_MODEL;

  FP_STAGE4(0, 0, Ag, Bg, D_MODEL, 0);
  FP_STAGE4(0, 1, Ag, Bg, D_MODEL, 32);

  const int NT = D_MODEL / 64;  // 16
  int buf = 0;
  for (int t = 0; t < NT; ++t) {
    const int tn = (t + 1 < NT) ? t + 1 : NT - 1;   // clamped dummy tail
    const int cb = tn * 64;
    FP_PHASE(buf, 0, buf ^ 1, 0, Ag, Bg, D_MODEL, cb,      1);
    FP_PHASE(buf, 1, buf ^ 1, 1, Ag, Bg, D_MODEL, cb + 32, 1);
    buf ^= 1;
  }
  asm volatile("s_waitcnt vmcnt(0)" ::: "memory");

  // epilogue (swapped layout): row M = mi*16+fr, col N = ni*16+fq*4+j -> 8B packed
  bf16* hout = hbuf + ((size_t)pair * SR + m0 + wm * 128) * D_FF + n0 + wn * 64;
#pragma unroll
  for (int mi = 0; mi < 8; ++mi) {
    const int row = mi * 16 + fr;
#pragma unroll
    for (int ni = 0; ni < 4; ++ni) {
      bf16x4 pk;
#pragma unroll
      for (int j = 0; j < 4; ++j) pk[j] = (bf16)(gelu_tanh(acc[mi][ni][j]) * wr);
      *(bf16x4*)(hout + (size_t)row * D_FF + ni * 16 + fq * 4) = pk;
    }
  }
}

// GEMM2: out += sum_r h[b,r] @ Wb[e_r]  (fat-phase, split-K=4, atomic f32 epilogue)
__launch_bounds__(512, 2)
__global__ void gemm2_kernel(const bf16* __restrict__ hbuf, const bf16* __restrict__ WbT,
                             const int* __restrict__ route_e,
                             float* __restrict__ out, int s_base, int SR) {
  __shared__ bf16 As[2 * 2 * 8192];
  __shared__ bf16 Bs[2 * 2 * 8192];
  int bx, by, bz;
  xcd_remap(bx, by, bz);
  const int b = bz >> 2;
  const int ksl = bz & 3;          // K quarter: tiles [ksl*48, ksl*48+48)
  const int m0 = by * 256;
  const int n0 = bx * 256;
  GEMM_DECLS
  f32x4 acc[8][4] = {};
  bf16x8 fA[8], fB[4];

  const int e0 = route_e[b * TOPK + 0];
  const int e1 = route_e[b * TOPK + 1];
  const int e2 = route_e[b * TOPK + 2];
  const bf16* Ar[3] = {
    hbuf + ((size_t)(b * TOPK + 0) * SR + m0) * D_FF,
    hbuf + ((size_t)(b * TOPK + 1) * SR + m0) * D_FF,
    hbuf + ((size_t)(b * TOPK + 2) * SR + m0) * D_FF };
  const bf16* Br[3] = {
    WbT + ((size_t)e0 * D_MODEL + n0) * D_FF,
    WbT + ((size_t)e1 * D_MODEL + n0) * D_FF,
    WbT + ((size_t)e2 * D_MODEL + n0) * D_FF };

  const int k0 = ksl * 48, NTk = 48;

  {
    const int rn = k0 >> 6, cb = (k0 & 63) * 64;
    FP_STAGE4(0, 0, Ar[rn], Br[rn], D_FF, cb);
    FP_STAGE4(0, 1, Ar[rn], Br[rn], D_FF, cb + 32);
  }

  int buf = 0;
  for (int t = 0; t < NTk; ++t) {
    const int gn = (t + 1 < NTk) ? k0 + t + 1 : k0 + NTk - 1;
    const int rn = gn >> 6;
    const int cb = (gn & 63) * 64;
    const bf16* SA = Ar[rn]; const bf16* SB = Br[rn];
    FP_PHASE(buf, 0, buf ^ 1, 0, SA, SB, D_FF, cb,      0);
    FP_PHASE(buf, 1, buf ^ 1, 1, SA, SB, D_FF, cb + 32, 0);
    buf ^= 1;
  }
  asm volatile("s_waitcnt vmcnt(0)" ::: "memory");

  // epilogue (unswapped layout): row = mi*16+fq*4+j, col = ni*16+fr
  // -> 16 lanes hit 16 consecutive 4B cols = full 64B lines (proven low WRITE_SIZE)
  const size_t ob = ((size_t)b * SEQ + (size_t)(s_base + m0 + wm * 128)) * D_MODEL + n0 + wn * 64;
#pragma unroll
  for (int mi = 0; mi < 8; ++mi)
#pragma unroll
    for (int ni = 0; ni < 4; ++ni)
#pragma unroll
      for (int j = 0; j < 4; ++j) {
        int row = mi * 16 + fq * 4 + j;
        float* pp = out + ob + (size_t)row * D_MODEL + ni * 16 + fr;
        float vv = acc[mi][ni][j];
        asm volatile("global_atomic_add_f32 %0, %1, off" :: "v"(pp), "v"(vv) : "memory");
      }
}

// ---------------- sentinel ----------------

__global__ void fail_kernel(float* out, float v) {
  if (threadIdx.x < 64) out[threadIdx.x] = v;
}

// ---------------- host ----------------

extern "C" void kernel_launch(void* const* d_in, const int* in_sizes, int n_in,
                              void* d_out, int out_size, void* d_ws, size_t ws_size,
                              hipStream_t stream) {
  const float* x  = (const float*)d_in[0];
  const float* W1 = (const float*)d_in[1];
  const float* b1 = (const float*)d_in[2];
  const float* W2 = (const float*)d_in[3];
  const float* b2 = (const float*)d_in[4];
  const float* Wa = (const float*)d_in[5];
  const float* Wb = (const float*)d_in[6];
  float* out = (float*)d_out;

  char* ws = (char*)d_ws;
  size_t off = 0;
  auto walloc = [&](size_t bytes) -> void* {
    void* p = ws + off;
    off += (bytes + 255) & ~(size_t)255;
    return p;
  };

  float* partial = (float*)walloc((size_t)8 * BATCH * D_MODEL * 4);
  float* pooled  = (float*)walloc((size_t)BATCH * D_MODEL * 4);
  int*   route_e = (int*)walloc(NPAIR * 4);
  float* route_w = (float*)walloc(NPAIR * 4);
  int*   perm    = (int*)walloc(NPAIR * 4);
  bf16*  xb      = (bf16*)walloc((size_t)BATCH * SEQ * D_MODEL * 2);
  bf16*  WaT     = (bf16*)walloc((size_t)N_ZONES * D_MODEL * D_FF * 2);
  bf16*  WbT     = (bf16*)walloc((size_t)N_ZONES * D_MODEL * D_FF * 2);
  size_t fixed = off;

  // SR=256: per-slice L3 working set (hbuf 96MB + WaT 64MB + WbT 64MB) fits 256MB L3
  const int SR = 256;
  if (fixed + (size_t)NPAIR * SR * D_FF * 2 + 1024 > ws_size) {
    fail_kernel<<<1, 64, 0, stream>>>(out, 1.0e6f + (float)(ws_size >> 20));
    return;
  }
  bf16* hbuf = (bf16*)walloc((size_t)NPAIR * SR * D_FF * 2);

  pool_partial_kernel<<<dim3(8, BATCH), 256, 0, stream>>>(x, partial);
  pool_final_kernel<<<BATCH, 256, 0, stream>>>(partial, pooled);
  router_kernel<<<BATCH, RH, 0, stream>>>(pooled, W1, b1, W2, b2, route_e, route_w);
  sort_pairs_kernel<<<1, 64, 0, stream>>>(route_e, perm);

  convert_x_kernel<<<(BATCH * SEQ * D_MODEL) / (256 * 8), 256, 0, stream>>>(x, xb, out);
  transpose_kernel<<<dim3(D_FF / 64, D_MODEL / 64, N_ZONES), 256, 0, stream>>>(Wa, WaT, D_MODEL, D_FF);
  transpose_kernel<<<dim3(D_MODEL / 64, D_FF / 64, N_ZONES), 256, 0, stream>>>(Wb, WbT, D_FF, D_MODEL);

  const int NS = SEQ / SR;   // 8 slices
  for (int sl = 0; sl < NS; ++sl) {
    gemm1_kernel<<<dim3(D_FF / 256, SR / 256, NPAIR), 512, 0, stream>>>(
        xb, WaT, route_e, route_w, perm, hbuf, sl * SR, SR);
    gemm2_kernel<<<dim3(D_MODEL / 256, SR / 256, BATCH * 4), 512, 0, stream>>>(
        hbuf, WbT, route_e, out, sl * SR, SR);
  }
}

// Round 13
// 2269.492 us; speedup vs baseline: 1.0282x; 1.0282x over previous
//
#include <hip/hip_runtime.h>
#include <hip/hip_bf16.h>
#include <stdint.h>

#define D_MODEL 1024
#define D_FF    4096
#define N_ZONES 8
#define TOPK    3
#define RH      256
#define BATCH   16
#define SEQ     2048
#define NPAIR   (BATCH * TOPK)

typedef __bf16 bf16;
typedef __bf16 bf16x8 __attribute__((ext_vector_type(8)));
typedef __bf16 bf16x4 __attribute__((ext_vector_type(4)));
typedef float  f32x4  __attribute__((ext_vector_type(4)));

// ---------------- helpers ----------------

__device__ __forceinline__ void gload16(const void* g, void* l) {
  __builtin_amdgcn_global_load_lds((const __attribute__((address_space(1))) void*)g,
                                   (__attribute__((address_space(3))) void*)l,
                                   16, 0, 0);
}

__device__ __forceinline__ float gelu_tanh(float x) {
  float inner = 0.7978845608028654f * (x + 0.044715f * x * x * x);
  float t = __expf(2.0f * inner);
  float th = 1.0f - 2.0f / (t + 1.0f);
  return 0.5f * x * (1.0f + th);
}

__device__ __forceinline__ void xcd_remap(int& bx, int& by, int& bz) {
  int lin = blockIdx.x + gridDim.x * (blockIdx.y + gridDim.y * blockIdx.z);
  int nwg = gridDim.x * gridDim.y * gridDim.z;
  int ns  = (lin & 7) * (nwg >> 3) + (lin >> 3);
  bx = ns % gridDim.x; int rest = ns / gridDim.x;
  by = rest % gridDim.y; bz = rest / gridDim.y;
}

// ---------------- pooling ----------------

__global__ void pool_partial_kernel(const float* __restrict__ x, float* __restrict__ partial) {
  int sc = blockIdx.x;
  int b  = blockIdx.y;
  int tid = threadIdx.x;
  const float* xp = x + ((size_t)b * SEQ + (size_t)sc * 256) * D_MODEL;
  for (int i = 0; i < D_MODEL / 256; ++i) {
    int d = tid + i * 256;
    float s = 0.f;
    for (int ss = 0; ss < 256; ++ss) s += xp[(size_t)ss * D_MODEL + d];
    partial[((size_t)sc * BATCH + b) * D_MODEL + d] = s;
  }
}

__global__ void pool_final_kernel(const float* __restrict__ partial, float* __restrict__ pooled) {
  int b = blockIdx.x;
  int tid = threadIdx.x;
  for (int i = 0; i < D_MODEL / 256; ++i) {
    int d = tid + i * 256;
    float s = 0.f;
    for (int sc = 0; sc < 8; ++sc) s += partial[((size_t)sc * BATCH + b) * D_MODEL + d];
    pooled[b * D_MODEL + d] = s * (1.0f / SEQ);
  }
}

// ---------------- router ----------------

__global__ void router_kernel(const float* __restrict__ pooled,
                              const float* __restrict__ W1, const float* __restrict__ b1,
                              const float* __restrict__ W2, const float* __restrict__ b2,
                              int* __restrict__ route_e, float* __restrict__ route_w) {
  __shared__ float pld[D_MODEL];
  __shared__ float hls[RH];
  __shared__ float lg[N_ZONES];
  const int b = blockIdx.x;
  const int j = threadIdx.x;

  for (int i = 0; i < D_MODEL / RH; ++i) pld[j + i * RH] = pooled[b * D_MODEL + j + i * RH];
  __syncthreads();

  float acc = b1[j];
#pragma unroll 8
  for (int k = 0; k < D_MODEL; ++k) acc += pld[k] * W1[k * RH + j];
  hls[j] = tanhf(acc);
  __syncthreads();

  if (j < N_ZONES) {
    float s = b2[j];
    for (int t = 0; t < RH; ++t) s += hls[t] * W2[t * N_ZONES + j];
    lg[j] = s;
  }
  __syncthreads();

  if (j == 0) {
    float m = lg[0];
    for (int e = 1; e < N_ZONES; ++e) m = fmaxf(m, lg[e]);
    float p[N_ZONES]; float sum = 0.f;
    for (int e = 0; e < N_ZONES; ++e) { p[e] = expf(lg[e] - m); sum += p[e]; }
    int used[N_ZONES] = {0};
    int idx[TOPK]; float tv[TOPK]; float tsum = 0.f;
    for (int r = 0; r < TOPK; ++r) {
      int best = 0; float bv = -1.f;
      for (int e = 0; e < N_ZONES; ++e)
        if (!used[e] && p[e] > bv) { bv = p[e]; best = e; }
      used[best] = 1; idx[r] = best; tv[r] = bv / sum; tsum += bv / sum;
    }
    for (int r = 0; r < TOPK; ++r) {
      route_e[b * TOPK + r] = idx[r];
      route_w[b * TOPK + r] = tv[r] / tsum;
    }
  }
}

__global__ void sort_pairs_kernel(const int* __restrict__ route_e, int* __restrict__ perm) {
  if (threadIdx.x == 0 && blockIdx.x == 0) {
    int p = 0;
    for (int e = 0; e < N_ZONES; ++e)
      for (int i = 0; i < NPAIR; ++i)
        if (route_e[i] == e) perm[p++] = i;
  }
}

// ---------------- conversions (convert + out-init fused) ----------------

__global__ void convert_x_kernel(const float* __restrict__ x, bf16* __restrict__ xb,
                                 float* __restrict__ out) {
  size_t i = ((size_t)blockIdx.x * blockDim.x + threadIdx.x) * 8;
  const float4* p = (const float4*)(x + i);
  float4 v0 = p[0], v1 = p[1];
  bf16x8 o;
  o[0] = (bf16)v0.x; o[1] = (bf16)v0.y; o[2] = (bf16)v0.z; o[3] = (bf16)v0.w;
  o[4] = (bf16)v1.x; o[5] = (bf16)v1.y; o[6] = (bf16)v1.z; o[7] = (bf16)v1.w;
  *(bf16x8*)(xb + i) = o;
  float4* q = (float4*)(out + i);
  q[0] = v0; q[1] = v1;                 // out pre-init to x (gemm2 atomic-adds on top)
}

__global__ void transpose_kernel(const float* __restrict__ src, bf16* __restrict__ dst, int R, int C) {
  __shared__ float tile[64][65];
  int e = blockIdx.z;
  const float* s = src + (size_t)e * R * C;
  bf16* d = dst + (size_t)e * R * C;
  int r0 = blockIdx.y * 64, c0 = blockIdx.x * 64;
  int tc = threadIdx.x & 63, tr4 = threadIdx.x >> 6;
  for (int i = 0; i < 16; ++i) {
    int r = i * 4 + tr4;
    tile[r][tc] = s[(size_t)(r0 + r) * C + (c0 + tc)];
  }
  __syncthreads();
  for (int i = 0; i < 16; ++i) {
    int cc = i * 4 + tr4;
    d[(size_t)(c0 + cc) * R + (r0 + tc)] = (bf16)tile[tc][cc];
  }
}

// ---------------- shared per-kernel decls ----------------

#define GEMM_DECLS                                                             \
  const int tid = threadIdx.x;                                                 \
  const int lane = tid & 63;                                                   \
  const int w = tid >> 6;                                                      \
  const int wm = w >> 2, wn = w & 3;                                           \
  const int fr = lane & 15, fq = lane >> 4;                                    \
  const int swz = (((lane & 3) ^ ((lane >> 3) & 3)) * 8);                      \
  const int swr = ((fq ^ ((fr >> 1) & 3)) * 8);                                \
  const int srow = lane >> 2;

// =====================================================================
// Fat-phase ring-2 core (r9/r10-proven best, 2176us): 256x256, BK=64
// (2 ksteps of 32). LDS As/Bs = [2 buf][2 ks][256x32] bf16 -> 128KB, 1 blk/CU.
// Phase (t,ks): vmcnt(4); barrier; free zone {12 ds_read (B first), stage 4
// gloads, 32 MFMA}; trailing sched_barrier(0).
// SR=512, gemm2 split-K=2 (r11 showed SR=256/splitK4 regresses: weight+RMW
// re-fetch per slice dominates over hbuf L3 residency).
// r12 change: gemm1 hbuf epilogue uses NONTEMPORAL stores -- hbuf is
// write-once-read-once (192MB/slice) and was evicting the WaT/WbT working
// set (128MB, reused all slices) from L3.
// =====================================================================

#define FP_STAGE4(buf_, ks_, SA_, SB_, ld_, kcb_)                              \
  { const bf16* _sa = (SA_) + (size_t)(w * 16 + srow) * (ld_) + (kcb_) + swz;  \
    bf16* _la = &As[((buf_) * 2 + (ks_)) * 8192] + w * 512;                    \
    gload16(_sa, _la);                                                         \
    gload16(_sa + (size_t)128 * (ld_), _la + 4096);                            \
    const bf16* _sb = (SB_) + (size_t)(w * 16 + srow) * (ld_) + (kcb_) + swz;  \
    bf16* _lb = &Bs[((buf_) * 2 + (ks_)) * 8192] + w * 512;                    \
    gload16(_sb, _lb);                                                         \
    gload16(_sb + (size_t)128 * (ld_), _lb + 4096); }

#define FP_DSRD12(buf_, ks_)                                                   \
  { const bf16* Bh = &Bs[((buf_) * 2 + (ks_)) * 8192] + (size_t)(wn * 64 + fr) * 32 + swr; \
    _Pragma("unroll")                                                          \
    for (int i = 0; i < 4; ++i) fB[i] = *(const bf16x8*)(Bh + i * 512);        \
    const bf16* Ah = &As[((buf_) * 2 + (ks_)) * 8192] + (size_t)(wm * 128 + fr) * 32 + swr; \
    _Pragma("unroll")                                                          \
    for (int i = 0; i < 8; ++i) fA[i] = *(const bf16x8*)(Ah + i * 512); }

// SWAP_: 1 = mfma(fB,fA) (cols packed by fq -> dense 8B stores), 0 = mfma(fA,fB)
// (rows by fq*4+j, cols by fr -> line-covering atomic layout).
#define FP_PHASE(rbuf_, rks_, sbuf_, sks_, SA_, SB_, ld_, kcb_, SWAP_)         \
  { asm volatile("s_waitcnt vmcnt(4)" ::: "memory");                           \
    __builtin_amdgcn_s_barrier();                                              \
    __builtin_amdgcn_sched_barrier(0);                                         \
    FP_DSRD12(rbuf_, rks_);                                                    \
    FP_STAGE4(sbuf_, sks_, SA_, SB_, ld_, kcb_);                               \
    __builtin_amdgcn_s_setprio(1);                                             \
    _Pragma("unroll")                                                          \
    for (int mi = 0; mi < 8; ++mi)                                             \
      _Pragma("unroll")                                                        \
      for (int ni = 0; ni < 4; ++ni)                                           \
        acc[mi][ni] = (SWAP_)                                                  \
          ? __builtin_amdgcn_mfma_f32_16x16x32_bf16(fB[ni], fA[mi], acc[mi][ni], 0, 0, 0) \
          : __builtin_amdgcn_mfma_f32_16x16x32_bf16(fA[mi], fB[ni], acc[mi][ni], 0, 0, 0); \
    __builtin_amdgcn_s_setprio(0);                                             \
    __builtin_amdgcn_sched_barrier(0); }

// GEMM1: h = gelu(xb @ Wa[e]) * w_r  (swapped operands -> dense packed epilogue)
__launch_bounds__(512, 2)
__global__ void gemm1_kernel(const bf16* __restrict__ xb, const bf16* __restrict__ WaT,
                             const int* __restrict__ route_e, const float* __restrict__ route_w,
                             const int* __restrict__ perm,
                             bf16* __restrict__ hbuf, int s_base, int SR) {
  __shared__ bf16 As[2 * 2 * 8192];
  __shared__ bf16 Bs[2 * 2 * 8192];
  int bx, by, bz;
  xcd_remap(bx, by, bz);
  const int pair = perm[bz];          // expert-sorted: XCD chunk shares WaT panels
  const int b = pair / TOPK;
  const int e = route_e[pair];
  const float wr = route_w[pair];
  const int m0 = by * 256;
  const int n0 = bx * 256;
  GEMM_DECLS
  f32x4 acc[8][4] = {};
  bf16x8 fA[8], fB[4];

  const bf16* Ag = xb  + ((size_t)b * SEQ + (size_t)(s_base + m0)) * D_MODEL;
  const bf16* Bg = WaT + ((size_t)e * D_FF + n0) * D_MODEL;

  FP_STAGE4(0, 0, Ag, Bg, D_MODEL, 0);
  FP_STAGE4(0, 1, Ag, Bg, D_MODEL, 32);

  const int NT = D_MODEL / 64;  // 16
  int buf = 0;
  for (int t = 0; t < NT; ++t) {
    const int tn = (t + 1 < NT) ? t + 1 : NT - 1;   // clamped dummy tail
    const int cb = tn * 64;
    FP_PHASE(buf, 0, buf ^ 1, 0, Ag, Bg, D_MODEL, cb,      1);
    FP_PHASE(buf, 1, buf ^ 1, 1, Ag, Bg, D_MODEL, cb + 32, 1);
    buf ^= 1;
  }
  asm volatile("s_waitcnt vmcnt(0)" ::: "memory");

  // epilogue (swapped layout): row M = mi*16+fr, col N = ni*16+fq*4+j -> 8B packed
  // NONTEMPORAL: hbuf is write-once-read-once; keep it out of L3 so weights stay.
  bf16* hout = hbuf + ((size_t)pair * SR + m0 + wm * 128) * D_FF + n0 + wn * 64;
#pragma unroll
  for (int mi = 0; mi < 8; ++mi) {
    const int row = mi * 16 + fr;
#pragma unroll
    for (int ni = 0; ni < 4; ++ni) {
      bf16x4 pk;
#pragma unroll
      for (int j = 0; j < 4; ++j) pk[j] = (bf16)(gelu_tanh(acc[mi][ni][j]) * wr);
      __builtin_nontemporal_store(pk, (bf16x4*)(hout + (size_t)row * D_FF + ni * 16 + fq * 4));
    }
  }
}

// GEMM2: out += sum_r h[b,r] @ Wb[e_r]  (fat-phase, split-K=2, atomic f32 epilogue)
__launch_bounds__(512, 2)
__global__ void gemm2_kernel(const bf16* __restrict__ hbuf, const bf16* __restrict__ WbT,
                             const int* __restrict__ route_e,
                             float* __restrict__ out, int s_base, int SR) {
  __shared__ bf16 As[2 * 2 * 8192];
  __shared__ bf16 Bs[2 * 2 * 8192];
  int bx, by, bz;
  xcd_remap(bx, by, bz);
  const int b = bz >> 1;
  const int ksl = bz & 1;          // K slice: tiles [ksl*96, ksl*96+96)
  const int m0 = by * 256;
  const int n0 = bx * 256;
  GEMM_DECLS
  f32x4 acc[8][4] = {};
  bf16x8 fA[8], fB[4];

  const int e0 = route_e[b * TOPK + 0];
  const int e1 = route_e[b * TOPK + 1];
  const int e2 = route_e[b * TOPK + 2];
  const bf16* Ar[3] = {
    hbuf + ((size_t)(b * TOPK + 0) * SR + m0) * D_FF,
    hbuf + ((size_t)(b * TOPK + 1) * SR + m0) * D_FF,
    hbuf + ((size_t)(b * TOPK + 2) * SR + m0) * D_FF };
  const bf16* Br[3] = {
    WbT + ((size_t)e0 * D_MODEL + n0) * D_FF,
    WbT + ((size_t)e1 * D_MODEL + n0) * D_FF,
    WbT + ((size_t)e2 * D_MODEL + n0) * D_FF };

  const int k0 = ksl * 96, NTk = 96;

  {
    const int rn = k0 >> 6, cb = (k0 & 63) * 64;
    FP_STAGE4(0, 0, Ar[rn], Br[rn], D_FF, cb);
    FP_STAGE4(0, 1, Ar[rn], Br[rn], D_FF, cb + 32);
  }

  int buf = 0;
  for (int t = 0; t < NTk; ++t) {
    const int gn = (t + 1 < NTk) ? k0 + t + 1 : k0 + NTk - 1;
    const int rn = gn >> 6;
    const int cb = (gn & 63) * 64;
    const bf16* SA = Ar[rn]; const bf16* SB = Br[rn];
    FP_PHASE(buf, 0, buf ^ 1, 0, SA, SB, D_FF, cb,      0);
    FP_PHASE(buf, 1, buf ^ 1, 1, SA, SB, D_FF, cb + 32, 0);
    buf ^= 1;
  }
  asm volatile("s_waitcnt vmcnt(0)" ::: "memory");

  // epilogue (unswapped layout): row = mi*16+fq*4+j, col = ni*16+fr
  // -> 16 lanes hit 16 consecutive 4B cols = full 64B lines (proven low WRITE_SIZE)
  const size_t ob = ((size_t)b * SEQ + (size_t)(s_base + m0 + wm * 128)) * D_MODEL + n0 + wn * 64;
#pragma unroll
  for (int mi = 0; mi < 8; ++mi)
#pragma unroll
    for (int ni = 0; ni < 4; ++ni)
#pragma unroll
      for (int j = 0; j < 4; ++j) {
        int row = mi * 16 + fq * 4 + j;
        float* pp = out + ob + (size_t)row * D_MODEL + ni * 16 + fr;
        float vv = acc[mi][ni][j];
        asm volatile("global_atomic_add_f32 %0, %1, off" :: "v"(pp), "v"(vv) : "memory");
      }
}

// ---------------- sentinel ----------------

__global__ void fail_kernel(float* out, float v) {
  if (threadIdx.x < 64) out[threadIdx.x] = v;
}

// ---------------- host ----------------

extern "C" void kernel_launch(void* const* d_in, const int* in_sizes, int n_in,
                              void* d_out, int out_size, void* d_ws, size_t ws_size,
                              hipStream_t stream) {
  const float* x  = (const float*)d_in[0];
  const float* W1 = (const float*)d_in[1];
  const float* b1 = (const float*)d_in[2];
  const float* W2 = (const float*)d_in[3];
  const float* b2 = (const float*)d_in[4];
  const float* Wa = (const float*)d_in[5];
  const float* Wb = (const float*)d_in[6];
  float* out = (float*)d_out;

  char* ws = (char*)d_ws;
  size_t off = 0;
  auto walloc = [&](size_t bytes) -> void* {
    void* p = ws + off;
    off += (bytes + 255) & ~(size_t)255;
    return p;
  };

  float* partial = (float*)walloc((size_t)8 * BATCH * D_MODEL * 4);
  float* pooled  = (float*)walloc((size_t)BATCH * D_MODEL * 4);
  int*   route_e = (int*)walloc(NPAIR * 4);
  float* route_w = (float*)walloc(NPAIR * 4);
  int*   perm    = (int*)walloc(NPAIR * 4);
  bf16*  xb      = (bf16*)walloc((size_t)BATCH * SEQ * D_MODEL * 2);
  bf16*  WaT     = (bf16*)walloc((size_t)N_ZONES * D_MODEL * D_FF * 2);
  bf16*  WbT     = (bf16*)walloc((size_t)N_ZONES * D_MODEL * D_FF * 2);
  size_t fixed = off;

  int SR = 0;
  const int cands[2] = {512, 256};
  for (int ci = 0; ci < 2; ++ci) {
    size_t need = fixed + (size_t)NPAIR * cands[ci] * D_FF * 2 + 1024;
    if (need <= ws_size) { SR = cands[ci]; break; }
  }
  if (SR == 0) {
    fail_kernel<<<1, 64, 0, stream>>>(out, 1.0e6f + (float)(ws_size >> 20));
    return;
  }
  bf16* hbuf = (bf16*)walloc((size_t)NPAIR * SR * D_FF * 2);

  pool_partial_kernel<<<dim3(8, BATCH), 256, 0, stream>>>(x, partial);
  pool_final_kernel<<<BATCH, 256, 0, stream>>>(partial, pooled);
  router_kernel<<<BATCH, RH, 0, stream>>>(pooled, W1, b1, W2, b2, route_e, route_w);
  sort_pairs_kernel<<<1, 64, 0, stream>>>(route_e, perm);

  convert_x_kernel<<<(BATCH * SEQ * D_MODEL) / (256 * 8), 256, 0, stream>>>(x, xb, out);
  transpose_kernel<<<dim3(D_FF / 64, D_MODEL / 64, N_ZONES), 256, 0, stream>>>(Wa, WaT, D_MODEL, D_FF);
  transpose_kernel<<<dim3(D_MODEL / 64, D_FF / 64, N_ZONES), 256, 0, stream>>>(Wb, WbT, D_FF, D_MODEL);

  const int NS = SEQ / SR;
  for (int sl = 0; sl < NS; ++sl) {
    gemm1_kernel<<<dim3(D_FF / 256, SR / 256, NPAIR), 512, 0, stream>>>(
        xb, WaT, route_e, route_w, perm, hbuf, sl * SR, SR);
    gemm2_kernel<<<dim3(D_MODEL / 256, SR / 256, BATCH * 2), 512, 0, stream>>>(
        hbuf, WbT, route_e, out, sl * SR, SR);
  }
}

// Round 14
// 2156.155 us; speedup vs baseline: 1.0823x; 1.0526x over previous
//
#include <hip/hip_runtime.h>
#include <hip/hip_bf16.h>
#include <stdint.h>

#define D_MODEL 1024
#define D_FF    4096
#define N_ZONES 8
#define TOPK    3
#define RH      256
#define BATCH   16
#define SEQ     2048
#define NPAIR   (BATCH * TOPK)

typedef __bf16 bf16;
typedef __bf16 bf16x8 __attribute__((ext_vector_type(8)));
typedef __bf16 bf16x4 __attribute__((ext_vector_type(4)));
typedef float  f32x4  __attribute__((ext_vector_type(4)));

// ---------------- helpers ----------------

__device__ __forceinline__ void gload16(const void* g, void* l) {
  __builtin_amdgcn_global_load_lds((const __attribute__((address_space(1))) void*)g,
                                   (__attribute__((address_space(3))) void*)l,
                                   16, 0, 0);
}

__device__ __forceinline__ float gelu_tanh(float x) {
  float inner = 0.7978845608028654f * (x + 0.044715f * x * x * x);
  float t = __expf(2.0f * inner);
  float th = 1.0f - 2.0f / (t + 1.0f);
  return 0.5f * x * (1.0f + th);
}

__device__ __forceinline__ void xcd_remap(int& bx, int& by, int& bz) {
  int lin = blockIdx.x + gridDim.x * (blockIdx.y + gridDim.y * blockIdx.z);
  int nwg = gridDim.x * gridDim.y * gridDim.z;
  int ns  = (lin & 7) * (nwg >> 3) + (lin >> 3);
  bx = ns % gridDim.x; int rest = ns / gridDim.x;
  by = rest % gridDim.y; bz = rest / gridDim.y;
}

// ---------------- pooling ----------------

__global__ void pool_partial_kernel(const float* __restrict__ x, float* __restrict__ partial) {
  int sc = blockIdx.x;
  int b  = blockIdx.y;
  int tid = threadIdx.x;
  const float* xp = x + ((size_t)b * SEQ + (size_t)sc * 256) * D_MODEL;
  for (int i = 0; i < D_MODEL / 256; ++i) {
    int d = tid + i * 256;
    float s = 0.f;
    for (int ss = 0; ss < 256; ++ss) s += xp[(size_t)ss * D_MODEL + d];
    partial[((size_t)sc * BATCH + b) * D_MODEL + d] = s;
  }
}

__global__ void pool_final_kernel(const float* __restrict__ partial, float* __restrict__ pooled) {
  int b = blockIdx.x;
  int tid = threadIdx.x;
  for (int i = 0; i < D_MODEL / 256; ++i) {
    int d = tid + i * 256;
    float s = 0.f;
    for (int sc = 0; sc < 8; ++sc) s += partial[((size_t)sc * BATCH + b) * D_MODEL + d];
    pooled[b * D_MODEL + d] = s * (1.0f / SEQ);
  }
}

// ---------------- router ----------------

__global__ void router_kernel(const float* __restrict__ pooled,
                              const float* __restrict__ W1, const float* __restrict__ b1,
                              const float* __restrict__ W2, const float* __restrict__ b2,
                              int* __restrict__ route_e, float* __restrict__ route_w) {
  __shared__ float pld[D_MODEL];
  __shared__ float hls[RH];
  __shared__ float lg[N_ZONES];
  const int b = blockIdx.x;
  const int j = threadIdx.x;

  for (int i = 0; i < D_MODEL / RH; ++i) pld[j + i * RH] = pooled[b * D_MODEL + j + i * RH];
  __syncthreads();

  float acc = b1[j];
#pragma unroll 8
  for (int k = 0; k < D_MODEL; ++k) acc += pld[k] * W1[k * RH + j];
  hls[j] = tanhf(acc);
  __syncthreads();

  if (j < N_ZONES) {
    float s = b2[j];
    for (int t = 0; t < RH; ++t) s += hls[t] * W2[t * N_ZONES + j];
    lg[j] = s;
  }
  __syncthreads();

  if (j == 0) {
    float m = lg[0];
    for (int e = 1; e < N_ZONES; ++e) m = fmaxf(m, lg[e]);
    float p[N_ZONES]; float sum = 0.f;
    for (int e = 0; e < N_ZONES; ++e) { p[e] = expf(lg[e] - m); sum += p[e]; }
    int used[N_ZONES] = {0};
    int idx[TOPK]; float tv[TOPK]; float tsum = 0.f;
    for (int r = 0; r < TOPK; ++r) {
      int best = 0; float bv = -1.f;
      for (int e = 0; e < N_ZONES; ++e)
        if (!used[e] && p[e] > bv) { bv = p[e]; best = e; }
      used[best] = 1; idx[r] = best; tv[r] = bv / sum; tsum += bv / sum;
    }
    for (int r = 0; r < TOPK; ++r) {
      route_e[b * TOPK + r] = idx[r];
      route_w[b * TOPK + r] = tv[r] / tsum;
    }
  }
}

__global__ void sort_pairs_kernel(const int* __restrict__ route_e, int* __restrict__ perm) {
  if (threadIdx.x == 0 && blockIdx.x == 0) {
    int p = 0;
    for (int e = 0; e < N_ZONES; ++e)
      for (int i = 0; i < NPAIR; ++i)
        if (route_e[i] == e) perm[p++] = i;
  }
}

// ---------------- conversions (convert + out-init fused) ----------------

__global__ void convert_x_kernel(const float* __restrict__ x, bf16* __restrict__ xb,
                                 float* __restrict__ out) {
  size_t i = ((size_t)blockIdx.x * blockDim.x + threadIdx.x) * 8;
  const float4* p = (const float4*)(x + i);
  float4 v0 = p[0], v1 = p[1];
  bf16x8 o;
  o[0] = (bf16)v0.x; o[1] = (bf16)v0.y; o[2] = (bf16)v0.z; o[3] = (bf16)v0.w;
  o[4] = (bf16)v1.x; o[5] = (bf16)v1.y; o[6] = (bf16)v1.z; o[7] = (bf16)v1.w;
  *(bf16x8*)(xb + i) = o;
  float4* q = (float4*)(out + i);
  q[0] = v0; q[1] = v1;                 // out pre-init to x (gemm2 atomic-adds on top)
}

__global__ void transpose_kernel(const float* __restrict__ src, bf16* __restrict__ dst, int R, int C) {
  __shared__ float tile[64][65];
  int e = blockIdx.z;
  const float* s = src + (size_t)e * R * C;
  bf16* d = dst + (size_t)e * R * C;
  int r0 = blockIdx.y * 64, c0 = blockIdx.x * 64;
  int tc = threadIdx.x & 63, tr4 = threadIdx.x >> 6;
  for (int i = 0; i < 16; ++i) {
    int r = i * 4 + tr4;
    tile[r][tc] = s[(size_t)(r0 + r) * C + (c0 + tc)];
  }
  __syncthreads();
  for (int i = 0; i < 16; ++i) {
    int cc = i * 4 + tr4;
    d[(size_t)(c0 + cc) * R + (r0 + tc)] = (bf16)tile[tc][cc];
  }
}

// ---------------- shared per-kernel decls ----------------

#define GEMM_DECLS                                                             \
  const int tid = threadIdx.x;                                                 \
  const int lane = tid & 63;                                                   \
  const int w = tid >> 6;                                                      \
  const int wm = w >> 2, wn = w & 3;                                           \
  const int fr = lane & 15, fq = lane >> 4;                                    \
  const int swz = (((lane & 3) ^ ((lane >> 3) & 3)) * 8);                      \
  const int swr = ((fq ^ ((fr >> 1) & 3)) * 8);                                \
  const int srow = lane >> 2;

// =====================================================================
// Fat-phase ring-2 core (r9/r10-proven best, 2176us): 256x256, BK=64
// (2 ksteps of 32). LDS As/Bs = [2 buf][2 ks][256x32] bf16 -> 128KB, 1 blk/CU.
// Phase (t,ks): vmcnt(4); barrier; free zone {12 ds_read (B first), stage 4
// gloads, 32 MFMA}; trailing sched_barrier(0).
// r13: gemm1 M-coarsened -- one block walks all SR/256 m-tiles of its pair,
// staging the NEXT m-tile's K-tile 0 in place of the old clamped dummy tail
// (seamless pipeline across the m boundary). Halves per-CU prologue/epilogue
// churn (1 blk/CU, sequential blocks can't overlap) and reuses the B panel
// in L2 across m-tiles. NT store from r12 REVERTED (WRITE_SIZE 196->433MB).
// =====================================================================

#define FP_STAGE4(buf_, ks_, SA_, SB_, ld_, kcb_)                              \
  { const bf16* _sa = (SA_) + (size_t)(w * 16 + srow) * (ld_) + (kcb_) + swz;  \
    bf16* _la = &As[((buf_) * 2 + (ks_)) * 8192] + w * 512;                    \
    gload16(_sa, _la);                                                         \
    gload16(_sa + (size_t)128 * (ld_), _la + 4096);                            \
    const bf16* _sb = (SB_) + (size_t)(w * 16 + srow) * (ld_) + (kcb_) + swz;  \
    bf16* _lb = &Bs[((buf_) * 2 + (ks_)) * 8192] + w * 512;                    \
    gload16(_sb, _lb);                                                         \
    gload16(_sb + (size_t)128 * (ld_), _lb + 4096); }

#define FP_DSRD12(buf_, ks_)                                                   \
  { const bf16* Bh = &Bs[((buf_) * 2 + (ks_)) * 8192] + (size_t)(wn * 64 + fr) * 32 + swr; \
    _Pragma("unroll")                                                          \
    for (int i = 0; i < 4; ++i) fB[i] = *(const bf16x8*)(Bh + i * 512);        \
    const bf16* Ah = &As[((buf_) * 2 + (ks_)) * 8192] + (size_t)(wm * 128 + fr) * 32 + swr; \
    _Pragma("unroll")                                                          \
    for (int i = 0; i < 8; ++i) fA[i] = *(const bf16x8*)(Ah + i * 512); }

// SWAP_: 1 = mfma(fB,fA) (cols packed by fq -> dense 8B stores), 0 = mfma(fA,fB)
// (rows by fq*4+j, cols by fr -> line-covering atomic layout).
#define FP_PHASE(rbuf_, rks_, sbuf_, sks_, SA_, SB_, ld_, kcb_, SWAP_)         \
  { asm volatile("s_waitcnt vmcnt(4)" ::: "memory");                           \
    __builtin_amdgcn_s_barrier();                                              \
    __builtin_amdgcn_sched_barrier(0);                                         \
    FP_DSRD12(rbuf_, rks_);                                                    \
    FP_STAGE4(sbuf_, sks_, SA_, SB_, ld_, kcb_);                               \
    __builtin_amdgcn_s_setprio(1);                                             \
    _Pragma("unroll")                                                          \
    for (int mi = 0; mi < 8; ++mi)                                             \
      _Pragma("unroll")                                                        \
      for (int ni = 0; ni < 4; ++ni)                                           \
        acc[mi][ni] = (SWAP_)                                                  \
          ? __builtin_amdgcn_mfma_f32_16x16x32_bf16(fB[ni], fA[mi], acc[mi][ni], 0, 0, 0) \
          : __builtin_amdgcn_mfma_f32_16x16x32_bf16(fA[mi], fB[ni], acc[mi][ni], 0, 0, 0); \
    __builtin_amdgcn_s_setprio(0);                                             \
    __builtin_amdgcn_sched_barrier(0); }

// GEMM1: h = gelu(xb @ Wa[e]) * w_r  (swapped operands -> dense packed epilogue)
// M-coarsened: grid (NFF, 1, NPAIR); block loops m-tiles 0..SR/256-1.
__launch_bounds__(512, 2)
__global__ void gemm1_kernel(const bf16* __restrict__ xb, const bf16* __restrict__ WaT,
                             const int* __restrict__ route_e, const float* __restrict__ route_w,
                             const int* __restrict__ perm,
                             bf16* __restrict__ hbuf, int s_base, int SR) {
  __shared__ bf16 As[2 * 2 * 8192];
  __shared__ bf16 Bs[2 * 2 * 8192];
  int bx, by, bz;
  xcd_remap(bx, by, bz);
  const int pair = perm[bz];          // expert-sorted: XCD chunk shares WaT panels
  const int b = pair / TOPK;
  const int e = route_e[pair];
  const float wr = route_w[pair];
  const int n0 = bx * 256;
  GEMM_DECLS
  f32x4 acc[8][4] = {};
  bf16x8 fA[8], fB[4];

  const bf16* AgBase = xb  + ((size_t)b * SEQ + (size_t)s_base) * D_MODEL;
  const bf16* Bg     = WaT + ((size_t)e * D_FF + n0) * D_MODEL;

  const int NT = D_MODEL / 64;          // 16 K-tiles per m-tile
  const int MS = SR / 256;              // m-tiles per block
  const int GMAX = MS * NT - 1;

  // prologue: global tile 0 (m-tile 0, K-tile 0), both ksteps -> buf 0
  FP_STAGE4(0, 0, AgBase, Bg, D_MODEL, 0);
  FP_STAGE4(0, 1, AgBase, Bg, D_MODEL, 32);

  int buf = 0;
  for (int mm = 0; mm < MS; ++mm) {
    for (int t = 0; t < NT; ++t) {
      int g = mm * NT + t + 1;          // next global tile (crosses m boundary)
      if (g > GMAX) g = GMAX;           // clamped dummy at the true end only
      const bf16* SAn = AgBase + (size_t)(g >> 4) * 256 * D_MODEL;
      const int cb = (g & (NT - 1)) * 64;
      FP_PHASE(buf, 0, buf ^ 1, 0, SAn, Bg, D_MODEL, cb,      1);
      FP_PHASE(buf, 1, buf ^ 1, 1, SAn, Bg, D_MODEL, cb + 32, 1);
      buf ^= 1;
    }
    // epilogue for m-tile mm (swapped layout): row M = mi*16+fr, col N = ni*16+fq*4+j
    bf16* hout = hbuf + ((size_t)pair * SR + mm * 256 + wm * 128) * D_FF + n0 + wn * 64;
#pragma unroll
    for (int mi = 0; mi < 8; ++mi) {
      const int row = mi * 16 + fr;
#pragma unroll
      for (int ni = 0; ni < 4; ++ni) {
        bf16x4 pk;
#pragma unroll
        for (int j = 0; j < 4; ++j) pk[j] = (bf16)(gelu_tanh(acc[mi][ni][j]) * wr);
        *(bf16x4*)(hout + (size_t)row * D_FF + ni * 16 + fq * 4) = pk;
      }
    }
    // reset accumulators for the next m-tile
#pragma unroll
    for (int mi = 0; mi < 8; ++mi)
#pragma unroll
      for (int ni = 0; ni < 4; ++ni)
        acc[mi][ni] = (f32x4){0.f, 0.f, 0.f, 0.f};
  }
  asm volatile("s_waitcnt vmcnt(0)" ::: "memory");
}

// GEMM2: out += sum_r h[b,r] @ Wb[e_r]  (fat-phase, split-K=2, atomic f32 epilogue)
__launch_bounds__(512, 2)
__global__ void gemm2_kernel(const bf16* __restrict__ hbuf, const bf16* __restrict__ WbT,
                             const int* __restrict__ route_e,
                             float* __restrict__ out, int s_base, int SR) {
  __shared__ bf16 As[2 * 2 * 8192];
  __shared__ bf16 Bs[2 * 2 * 8192];
  int bx, by, bz;
  xcd_remap(bx, by, bz);
  const int b = bz >> 1;
  const int ksl = bz & 1;          // K slice: tiles [ksl*96, ksl*96+96)
  const int m0 = by * 256;
  const int n0 = bx * 256;
  GEMM_DECLS
  f32x4 acc[8][4] = {};
  bf16x8 fA[8], fB[4];

  const int e0 = route_e[b * TOPK + 0];
  const int e1 = route_e[b * TOPK + 1];
  const int e2 = route_e[b * TOPK + 2];
  const bf16* Ar[3] = {
    hbuf + ((size_t)(b * TOPK + 0) * SR + m0) * D_FF,
    hbuf + ((size_t)(b * TOPK + 1) * SR + m0) * D_FF,
    hbuf + ((size_t)(b * TOPK + 2) * SR + m0) * D_FF };
  const bf16* Br[3] = {
    WbT + ((size_t)e0 * D_MODEL + n0) * D_FF,
    WbT + ((size_t)e1 * D_MODEL + n0) * D_FF,
    WbT + ((size_t)e2 * D_MODEL + n0) * D_FF };

  const int k0 = ksl * 96, NTk = 96;

  {
    const int rn = k0 >> 6, cb = (k0 & 63) * 64;
    FP_STAGE4(0, 0, Ar[rn], Br[rn], D_FF, cb);
    FP_STAGE4(0, 1, Ar[rn], Br[rn], D_FF, cb + 32);
  }

  int buf = 0;
  for (int t = 0; t < NTk; ++t) {
    const int gn = (t + 1 < NTk) ? k0 + t + 1 : k0 + NTk - 1;
    const int rn = gn >> 6;
    const int cb = (gn & 63) * 64;
    const bf16* SA = Ar[rn]; const bf16* SB = Br[rn];
    FP_PHASE(buf, 0, buf ^ 1, 0, SA, SB, D_FF, cb,      0);
    FP_PHASE(buf, 1, buf ^ 1, 1, SA, SB, D_FF, cb + 32, 0);
    buf ^= 1;
  }
  asm volatile("s_waitcnt vmcnt(0)" ::: "memory");

  // epilogue (unswapped layout): row = mi*16+fq*4+j, col = ni*16+fr
  // -> 16 lanes hit 16 consecutive 4B cols = full 64B lines (proven low WRITE_SIZE)
  const size_t ob = ((size_t)b * SEQ + (size_t)(s_base + m0 + wm * 128)) * D_MODEL + n0 + wn * 64;
#pragma unroll
  for (int mi = 0; mi < 8; ++mi)
#pragma unroll
    for (int ni = 0; ni < 4; ++ni)
#pragma unroll
      for (int j = 0; j < 4; ++j) {
        int row = mi * 16 + fq * 4 + j;
        float* pp = out + ob + (size_t)row * D_MODEL + ni * 16 + fr;
        float vv = acc[mi][ni][j];
        asm volatile("global_atomic_add_f32 %0, %1, off" :: "v"(pp), "v"(vv) : "memory");
      }
}

// ---------------- sentinel ----------------

__global__ void fail_kernel(float* out, float v) {
  if (threadIdx.x < 64) out[threadIdx.x] = v;
}

// ---------------- host ----------------

extern "C" void kernel_launch(void* const* d_in, const int* in_sizes, int n_in,
                              void* d_out, int out_size, void* d_ws, size_t ws_size,
                              hipStream_t stream) {
  const float* x  = (const float*)d_in[0];
  const float* W1 = (const float*)d_in[1];
  const float* b1 = (const float*)d_in[2];
  const float* W2 = (const float*)d_in[3];
  const float* b2 = (const float*)d_in[4];
  const float* Wa = (const float*)d_in[5];
  const float* Wb = (const float*)d_in[6];
  float* out = (float*)d_out;

  char* ws = (char*)d_ws;
  size_t off = 0;
  auto walloc = [&](size_t bytes) -> void* {
    void* p = ws + off;
    off += (bytes + 255) & ~(size_t)255;
    return p;
  };

  float* partial = (float*)walloc((size_t)8 * BATCH * D_MODEL * 4);
  float* pooled  = (float*)walloc((size_t)BATCH * D_MODEL * 4);
  int*   route_e = (int*)walloc(NPAIR * 4);
  float* route_w = (float*)walloc(NPAIR * 4);
  int*   perm    = (int*)walloc(NPAIR * 4);
  bf16*  xb      = (bf16*)walloc((size_t)BATCH * SEQ * D_MODEL * 2);
  bf16*  WaT     = (bf16*)walloc((size_t)N_ZONES * D_MODEL * D_FF * 2);
  bf16*  WbT     = (bf16*)walloc((size_t)N_ZONES * D_MODEL * D_FF * 2);
  size_t fixed = off;

  int SR = 0;
  const int cands[2] = {512, 256};
  for (int ci = 0; ci < 2; ++ci) {
    size_t need = fixed + (size_t)NPAIR * cands[ci] * D_FF * 2 + 1024;
    if (need <= ws_size) { SR = cands[ci]; break; }
  }
  if (SR == 0) {
    fail_kernel<<<1, 64, 0, stream>>>(out, 1.0e6f + (float)(ws_size >> 20));
    return;
  }
  bf16* hbuf = (bf16*)walloc((size_t)NPAIR * SR * D_FF * 2);

  pool_partial_kernel<<<dim3(8, BATCH), 256, 0, stream>>>(x, partial);
  pool_final_kernel<<<BATCH, 256, 0, stream>>>(partial, pooled);
  router_kernel<<<BATCH, RH, 0, stream>>>(pooled, W1, b1, W2, b2, route_e, route_w);
  sort_pairs_kernel<<<1, 64, 0, stream>>>(route_e, perm);

  convert_x_kernel<<<(BATCH * SEQ * D_MODEL) / (256 * 8), 256, 0, stream>>>(x, xb, out);
  transpose_kernel<<<dim3(D_FF / 64, D_MODEL / 64, N_ZONES), 256, 0, stream>>>(Wa, WaT, D_MODEL, D_FF);
  transpose_kernel<<<dim3(D_MODEL / 64, D_FF / 64, N_ZONES), 256, 0, stream>>>(Wb, WbT, D_FF, D_MODEL);

  const int NS = SEQ / SR;
  for (int sl = 0; sl < NS; ++sl) {
    gemm1_kernel<<<dim3(D_FF / 256, 1, NPAIR), 512, 0, stream>>>(
        xb, WaT, route_e, route_w, perm, hbuf, sl * SR, SR);
    gemm2_kernel<<<dim3(D_MODEL / 256, SR / 256, BATCH * 2), 512, 0, stream>>>(
        hbuf, WbT, route_e, out, sl * SR, SR);
  }
}

// Round 15
// 2110.415 us; speedup vs baseline: 1.1057x; 1.0217x over previous
//
#include <hip/hip_runtime.h>
#include <hip/hip_bf16.h>
#include <stdint.h>

#define D_MODEL 1024
#define D_FF    4096
#define N_ZONES 8
#define TOPK    3
#define RH      256
#define BATCH   16
#define SEQ     2048
#define NPAIR   (BATCH * TOPK)
#define PCHUNK  16   // pooling chunks (128 rows each)

typedef __bf16 bf16;
typedef __bf16 bf16x8 __attribute__((ext_vector_type(8)));
typedef __bf16 bf16x4 __attribute__((ext_vector_type(4)));
typedef float  f32x4  __attribute__((ext_vector_type(4)));

// ---------------- helpers ----------------

__device__ __forceinline__ void gload16(const void* g, void* l) {
  __builtin_amdgcn_global_load_lds((const __attribute__((address_space(1))) void*)g,
                                   (__attribute__((address_space(3))) void*)l,
                                   16, 0, 0);
}

__device__ __forceinline__ float gelu_tanh(float x) {
  float inner = 0.7978845608028654f * (x + 0.044715f * x * x * x);
  float t = __expf(2.0f * inner);
  float th = 1.0f - 2.0f / (t + 1.0f);
  return 0.5f * x * (1.0f + th);
}

__device__ __forceinline__ void xcd_remap(int& bx, int& by, int& bz) {
  int lin = blockIdx.x + gridDim.x * (blockIdx.y + gridDim.y * blockIdx.z);
  int nwg = gridDim.x * gridDim.y * gridDim.z;
  int ns  = (lin & 7) * (nwg >> 3) + (lin >> 3);
  bx = ns % gridDim.x; int rest = ns / gridDim.x;
  by = rest % gridDim.y; bz = rest / gridDim.y;
}

// ---------------- fused convert + out-init + pooling partials ----------------
// One pass over x: write bf16 copy, f32 copy to out, and per-chunk column sums.
// Replaces the old separate pool_partial (second 128MB read of x eliminated).

__global__ void convert_pool_kernel(const float* __restrict__ x, bf16* __restrict__ xb,
                                    float* __restrict__ out, float* __restrict__ partial) {
  const int sc = blockIdx.x;        // PCHUNK chunks of SEQ/PCHUNK=128 rows
  const int b  = blockIdx.y;
  const int t  = threadIdx.x;       // 256 threads; thread owns cols [4t..4t+3]
  const size_t base = ((size_t)b * SEQ + (size_t)sc * (SEQ / PCHUNK)) * D_MODEL;
  const float4* xp = (const float4*)(x + base);
  float4* op = (float4*)(out + base);
  bf16* xbp = xb + base;
  float4 s = {0.f, 0.f, 0.f, 0.f};
  for (int r = 0; r < SEQ / PCHUNK; ++r) {
    float4 v = xp[(size_t)r * 256 + t];
    s.x += v.x; s.y += v.y; s.z += v.z; s.w += v.w;
    op[(size_t)r * 256 + t] = v;
    bf16x4 o;
    o[0] = (bf16)v.x; o[1] = (bf16)v.y; o[2] = (bf16)v.z; o[3] = (bf16)v.w;
    *(bf16x4*)(xbp + (size_t)r * D_MODEL + t * 4) = o;
  }
  *(float4*)(partial + ((size_t)sc * BATCH + b) * D_MODEL + t * 4) = s;
}

__global__ void pool_final_kernel(const float* __restrict__ partial, float* __restrict__ pooled) {
  int b = blockIdx.x;
  int tid = threadIdx.x;
  for (int i = 0; i < D_MODEL / 256; ++i) {
    int d = tid + i * 256;
    float s = 0.f;
    for (int sc = 0; sc < PCHUNK; ++sc) s += partial[((size_t)sc * BATCH + b) * D_MODEL + d];
    pooled[b * D_MODEL + d] = s * (1.0f / SEQ);
  }
}

// ---------------- router ----------------

__global__ void router_kernel(const float* __restrict__ pooled,
                              const float* __restrict__ W1, const float* __restrict__ b1,
                              const float* __restrict__ W2, const float* __restrict__ b2,
                              int* __restrict__ route_e, float* __restrict__ route_w) {
  __shared__ float pld[D_MODEL];
  __shared__ float hls[RH];
  __shared__ float lg[N_ZONES];
  const int b = blockIdx.x;
  const int j = threadIdx.x;

  for (int i = 0; i < D_MODEL / RH; ++i) pld[j + i * RH] = pooled[b * D_MODEL + j + i * RH];
  __syncthreads();

  float acc = b1[j];
#pragma unroll 8
  for (int k = 0; k < D_MODEL; ++k) acc += pld[k] * W1[k * RH + j];
  hls[j] = tanhf(acc);
  __syncthreads();

  if (j < N_ZONES) {
    float s = b2[j];
    for (int t = 0; t < RH; ++t) s += hls[t] * W2[t * N_ZONES + j];
    lg[j] = s;
  }
  __syncthreads();

  if (j == 0) {
    float m = lg[0];
    for (int e = 1; e < N_ZONES; ++e) m = fmaxf(m, lg[e]);
    float p[N_ZONES]; float sum = 0.f;
    for (int e = 0; e < N_ZONES; ++e) { p[e] = expf(lg[e] - m); sum += p[e]; }
    int used[N_ZONES] = {0};
    int idx[TOPK]; float tv[TOPK]; float tsum = 0.f;
    for (int r = 0; r < TOPK; ++r) {
      int best = 0; float bv = -1.f;
      for (int e = 0; e < N_ZONES; ++e)
        if (!used[e] && p[e] > bv) { bv = p[e]; best = e; }
      used[best] = 1; idx[r] = best; tv[r] = bv / sum; tsum += bv / sum;
    }
    for (int r = 0; r < TOPK; ++r) {
      route_e[b * TOPK + r] = idx[r];
      route_w[b * TOPK + r] = tv[r] / tsum;
    }
  }
}

__global__ void sort_pairs_kernel(const int* __restrict__ route_e, int* __restrict__ perm) {
  if (threadIdx.x == 0 && blockIdx.x == 0) {
    int p = 0;
    for (int e = 0; e < N_ZONES; ++e)
      for (int i = 0; i < NPAIR; ++i)
        if (route_e[i] == e) perm[p++] = i;
  }
}

// ---------------- weight transposes ----------------

__global__ void transpose_kernel(const float* __restrict__ src, bf16* __restrict__ dst, int R, int C) {
  __shared__ float tile[64][65];
  int e = blockIdx.z;
  const float* s = src + (size_t)e * R * C;
  bf16* d = dst + (size_t)e * R * C;
  int r0 = blockIdx.y * 64, c0 = blockIdx.x * 64;
  int tc = threadIdx.x & 63, tr4 = threadIdx.x >> 6;
  for (int i = 0; i < 16; ++i) {
    int r = i * 4 + tr4;
    tile[r][tc] = s[(size_t)(r0 + r) * C + (c0 + tc)];
  }
  __syncthreads();
  for (int i = 0; i < 16; ++i) {
    int cc = i * 4 + tr4;
    d[(size_t)(c0 + cc) * R + (r0 + tc)] = (bf16)tile[tc][cc];
  }
}

// ---------------- shared per-kernel decls ----------------

#define GEMM_DECLS                                                             \
  const int tid = threadIdx.x;                                                 \
  const int lane = tid & 63;                                                   \
  const int w = tid >> 6;                                                      \
  const int wm = w >> 2, wn = w & 3;                                           \
  const int fr = lane & 15, fq = lane >> 4;                                    \
  const int swz = (((lane & 3) ^ ((lane >> 3) & 3)) * 8);                      \
  const int swr = ((fq ^ ((fr >> 1) & 3)) * 8);                                \
  const int srow = lane >> 2;

// =====================================================================
// Fat-phase ring-2 core (r13-proven best, 2156us): 256x256, BK=64
// (2 ksteps of 32). LDS As/Bs = [2 buf][2 ks][256x32] bf16 -> 128KB, 1 blk/CU.
// Phase (t,ks): vmcnt(4); barrier; free zone {12 ds_read (B first), stage 4
// gloads, 32 MFMA}; trailing sched_barrier(0).
// gemm1 M-coarsened (r13); gemm2 split-K=2 with line-covering atomics (r8).
// r14 change: convert+pool fused (one less 128MB pass over x). GEMMs untouched.
// =====================================================================

#define FP_STAGE4(buf_, ks_, SA_, SB_, ld_, kcb_)                              \
  { const bf16* _sa = (SA_) + (size_t)(w * 16 + srow) * (ld_) + (kcb_) + swz;  \
    bf16* _la = &As[((buf_) * 2 + (ks_)) * 8192] + w * 512;                    \
    gload16(_sa, _la);                                                         \
    gload16(_sa + (size_t)128 * (ld_), _la + 4096);                            \
    const bf16* _sb = (SB_) + (size_t)(w * 16 + srow) * (ld_) + (kcb_) + swz;  \
    bf16* _lb = &Bs[((buf_) * 2 + (ks_)) * 8192] + w * 512;                    \
    gload16(_sb, _lb);                                                         \
    gload16(_sb + (size_t)128 * (ld_), _lb + 4096); }

#define FP_DSRD12(buf_, ks_)                                                   \
  { const bf16* Bh = &Bs[((buf_) * 2 + (ks_)) * 8192] + (size_t)(wn * 64 + fr) * 32 + swr; \
    _Pragma("unroll")                                                          \
    for (int i = 0; i < 4; ++i) fB[i] = *(const bf16x8*)(Bh + i * 512);        \
    const bf16* Ah = &As[((buf_) * 2 + (ks_)) * 8192] + (size_t)(wm * 128 + fr) * 32 + swr; \
    _Pragma("unroll")                                                          \
    for (int i = 0; i < 8; ++i) fA[i] = *(const bf16x8*)(Ah + i * 512); }

// SWAP_: 1 = mfma(fB,fA) (cols packed by fq -> dense 8B stores), 0 = mfma(fA,fB)
// (rows by fq*4+j, cols by fr -> line-covering atomic layout).
#define FP_PHASE(rbuf_, rks_, sbuf_, sks_, SA_, SB_, ld_, kcb_, SWAP_)         \
  { asm volatile("s_waitcnt vmcnt(4)" ::: "memory");                           \
    __builtin_amdgcn_s_barrier();                                              \
    __builtin_amdgcn_sched_barrier(0);                                         \
    FP_DSRD12(rbuf_, rks_);                                                    \
    FP_STAGE4(sbuf_, sks_, SA_, SB_, ld_, kcb_);                               \
    __builtin_amdgcn_s_setprio(1);                                             \
    _Pragma("unroll")                                                          \
    for (int mi = 0; mi < 8; ++mi)                                             \
      _Pragma("unroll")                                                        \
      for (int ni = 0; ni < 4; ++ni)                                           \
        acc[mi][ni] = (SWAP_)                                                  \
          ? __builtin_amdgcn_mfma_f32_16x16x32_bf16(fB[ni], fA[mi], acc[mi][ni], 0, 0, 0) \
          : __builtin_amdgcn_mfma_f32_16x16x32_bf16(fA[mi], fB[ni], acc[mi][ni], 0, 0, 0); \
    __builtin_amdgcn_s_setprio(0);                                             \
    __builtin_amdgcn_sched_barrier(0); }

// GEMM1: h = gelu(xb @ Wa[e]) * w_r  (swapped operands -> dense packed epilogue)
// M-coarsened: grid (NFF, 1, NPAIR); block loops m-tiles 0..SR/256-1.
__launch_bounds__(512, 2)
__global__ void gemm1_kernel(const bf16* __restrict__ xb, const bf16* __restrict__ WaT,
                             const int* __restrict__ route_e, const float* __restrict__ route_w,
                             const int* __restrict__ perm,
                             bf16* __restrict__ hbuf, int s_base, int SR) {
  __shared__ bf16 As[2 * 2 * 8192];
  __shared__ bf16 Bs[2 * 2 * 8192];
  int bx, by, bz;
  xcd_remap(bx, by, bz);
  const int pair = perm[bz];          // expert-sorted: XCD chunk shares WaT panels
  const int b = pair / TOPK;
  const int e = route_e[pair];
  const float wr = route_w[pair];
  const int n0 = bx * 256;
  GEMM_DECLS
  f32x4 acc[8][4] = {};
  bf16x8 fA[8], fB[4];

  const bf16* AgBase = xb  + ((size_t)b * SEQ + (size_t)s_base) * D_MODEL;
  const bf16* Bg     = WaT + ((size_t)e * D_FF + n0) * D_MODEL;

  const int NT = D_MODEL / 64;          // 16 K-tiles per m-tile
  const int MS = SR / 256;              // m-tiles per block
  const int GMAX = MS * NT - 1;

  // prologue: global tile 0 (m-tile 0, K-tile 0), both ksteps -> buf 0
  FP_STAGE4(0, 0, AgBase, Bg, D_MODEL, 0);
  FP_STAGE4(0, 1, AgBase, Bg, D_MODEL, 32);

  int buf = 0;
  for (int mm = 0; mm < MS; ++mm) {
    for (int t = 0; t < NT; ++t) {
      int g = mm * NT + t + 1;          // next global tile (crosses m boundary)
      if (g > GMAX) g = GMAX;           // clamped dummy at the true end only
      const bf16* SAn = AgBase + (size_t)(g >> 4) * 256 * D_MODEL;
      const int cb = (g & (NT - 1)) * 64;
      FP_PHASE(buf, 0, buf ^ 1, 0, SAn, Bg, D_MODEL, cb,      1);
      FP_PHASE(buf, 1, buf ^ 1, 1, SAn, Bg, D_MODEL, cb + 32, 1);
      buf ^= 1;
    }
    // epilogue for m-tile mm (swapped layout): row M = mi*16+fr, col N = ni*16+fq*4+j
    bf16* hout = hbuf + ((size_t)pair * SR + mm * 256 + wm * 128) * D_FF + n0 + wn * 64;
#pragma unroll
    for (int mi = 0; mi < 8; ++mi) {
      const int row = mi * 16 + fr;
#pragma unroll
      for (int ni = 0; ni < 4; ++ni) {
        bf16x4 pk;
#pragma unroll
        for (int j = 0; j < 4; ++j) pk[j] = (bf16)(gelu_tanh(acc[mi][ni][j]) * wr);
        *(bf16x4*)(hout + (size_t)row * D_FF + ni * 16 + fq * 4) = pk;
      }
    }
    // reset accumulators for the next m-tile
#pragma unroll
    for (int mi = 0; mi < 8; ++mi)
#pragma unroll
      for (int ni = 0; ni < 4; ++ni)
        acc[mi][ni] = (f32x4){0.f, 0.f, 0.f, 0.f};
  }
  asm volatile("s_waitcnt vmcnt(0)" ::: "memory");
}

// GEMM2: out += sum_r h[b,r] @ Wb[e_r]  (fat-phase, split-K=2, atomic f32 epilogue)
__launch_bounds__(512, 2)
__global__ void gemm2_kernel(const bf16* __restrict__ hbuf, const bf16* __restrict__ WbT,
                             const int* __restrict__ route_e,
                             float* __restrict__ out, int s_base, int SR) {
  __shared__ bf16 As[2 * 2 * 8192];
  __shared__ bf16 Bs[2 * 2 * 8192];
  int bx, by, bz;
  xcd_remap(bx, by, bz);
  const int b = bz >> 1;
  const int ksl = bz & 1;          // K slice: tiles [ksl*96, ksl*96+96)
  const int m0 = by * 256;
  const int n0 = bx * 256;
  GEMM_DECLS
  f32x4 acc[8][4] = {};
  bf16x8 fA[8], fB[4];

  const int e0 = route_e[b * TOPK + 0];
  const int e1 = route_e[b * TOPK + 1];
  const int e2 = route_e[b * TOPK + 2];
  const bf16* Ar[3] = {
    hbuf + ((size_t)(b * TOPK + 0) * SR + m0) * D_FF,
    hbuf + ((size_t)(b * TOPK + 1) * SR + m0) * D_FF,
    hbuf + ((size_t)(b * TOPK + 2) * SR + m0) * D_FF };
  const bf16* Br[3] = {
    WbT + ((size_t)e0 * D_MODEL + n0) * D_FF,
    WbT + ((size_t)e1 * D_MODEL + n0) * D_FF,
    WbT + ((size_t)e2 * D_MODEL + n0) * D_FF };

  const int k0 = ksl * 96, NTk = 96;

  {
    const int rn = k0 >> 6, cb = (k0 & 63) * 64;
    FP_STAGE4(0, 0, Ar[rn], Br[rn], D_FF, cb);
    FP_STAGE4(0, 1, Ar[rn], Br[rn], D_FF, cb + 32);
  }

  int buf = 0;
  for (int t = 0; t < NTk; ++t) {
    const int gn = (t + 1 < NTk) ? k0 + t + 1 : k0 + NTk - 1;
    const int rn = gn >> 6;
    const int cb = (gn & 63) * 64;
    const bf16* SA = Ar[rn]; const bf16* SB = Br[rn];
    FP_PHASE(buf, 0, buf ^ 1, 0, SA, SB, D_FF, cb,      0);
    FP_PHASE(buf, 1, buf ^ 1, 1, SA, SB, D_FF, cb + 32, 0);
    buf ^= 1;
  }
  asm volatile("s_waitcnt vmcnt(0)" ::: "memory");

  // epilogue (unswapped layout): row = mi*16+fq*4+j, col = ni*16+fr
  // -> 16 lanes hit 16 consecutive 4B cols = full 64B lines (proven low WRITE_SIZE)
  const size_t ob = ((size_t)b * SEQ + (size_t)(s_base + m0 + wm * 128)) * D_MODEL + n0 + wn * 64;
#pragma unroll
  for (int mi = 0; mi < 8; ++mi)
#pragma unroll
    for (int ni = 0; ni < 4; ++ni)
#pragma unroll
      for (int j = 0; j < 4; ++j) {
        int row = mi * 16 + fq * 4 + j;
        float* pp = out + ob + (size_t)row * D_MODEL + ni * 16 + fr;
        float vv = acc[mi][ni][j];
        asm volatile("global_atomic_add_f32 %0, %1, off" :: "v"(pp), "v"(vv) : "memory");
      }
}

// ---------------- sentinel ----------------

__global__ void fail_kernel(float* out, float v) {
  if (threadIdx.x < 64) out[threadIdx.x] = v;
}

// ---------------- host ----------------

extern "C" void kernel_launch(void* const* d_in, const int* in_sizes, int n_in,
                              void* d_out, int out_size, void* d_ws, size_t ws_size,
                              hipStream_t stream) {
  const float* x  = (const float*)d_in[0];
  const float* W1 = (const float*)d_in[1];
  const float* b1 = (const float*)d_in[2];
  const float* W2 = (const float*)d_in[3];
  const float* b2 = (const float*)d_in[4];
  const float* Wa = (const float*)d_in[5];
  const float* Wb = (const float*)d_in[6];
  float* out = (float*)d_out;

  char* ws = (char*)d_ws;
  size_t off = 0;
  auto walloc = [&](size_t bytes) -> void* {
    void* p = ws + off;
    off += (bytes + 255) & ~(size_t)255;
    return p;
  };

  float* partial = (float*)walloc((size_t)PCHUNK * BATCH * D_MODEL * 4);
  float* pooled  = (float*)walloc((size_t)BATCH * D_MODEL * 4);
  int*   route_e = (int*)walloc(NPAIR * 4);
  float* route_w = (float*)walloc(NPAIR * 4);
  int*   perm    = (int*)walloc(NPAIR * 4);
  bf16*  xb      = (bf16*)walloc((size_t)BATCH * SEQ * D_MODEL * 2);
  bf16*  WaT     = (bf16*)walloc((size_t)N_ZONES * D_MODEL * D_FF * 2);
  bf16*  WbT     = (bf16*)walloc((size_t)N_ZONES * D_MODEL * D_FF * 2);
  size_t fixed = off;

  int SR = 0;
  const int cands[2] = {512, 256};
  for (int ci = 0; ci < 2; ++ci) {
    size_t need = fixed + (size_t)NPAIR * cands[ci] * D_FF * 2 + 1024;
    if (need <= ws_size) { SR = cands[ci]; break; }
  }
  if (SR == 0) {
    fail_kernel<<<1, 64, 0, stream>>>(out, 1.0e6f + (float)(ws_size >> 20));
    return;
  }
  bf16* hbuf = (bf16*)walloc((size_t)NPAIR * SR * D_FF * 2);

  // fused: x -> {xb, out-init, pooling partials} in one pass
  convert_pool_kernel<<<dim3(PCHUNK, BATCH), 256, 0, stream>>>(x, xb, out, partial);
  pool_final_kernel<<<BATCH, 256, 0, stream>>>(partial, pooled);
  router_kernel<<<BATCH, RH, 0, stream>>>(pooled, W1, b1, W2, b2, route_e, route_w);
  sort_pairs_kernel<<<1, 64, 0, stream>>>(route_e, perm);

  transpose_kernel<<<dim3(D_FF / 64, D_MODEL / 64, N_ZONES), 256, 0, stream>>>(Wa, WaT, D_MODEL, D_FF);
  transpose_kernel<<<dim3(D_MODEL / 64, D_FF / 64, N_ZONES), 256, 0, stream>>>(Wb, WbT, D_FF, D_MODEL);

  const int NS = SEQ / SR;
  for (int sl = 0; sl < NS; ++sl) {
    gemm1_kernel<<<dim3(D_FF / 256, 1, NPAIR), 512, 0, stream>>>(
        xb, WaT, route_e, route_w, perm, hbuf, sl * SR, SR);
    gemm2_kernel<<<dim3(D_MODEL / 256, SR / 256, BATCH * 2), 512, 0, stream>>>(
        hbuf, WbT, route_e, out, sl * SR, SR);
  }
}